// Round 6
// baseline (341.299 us; speedup 1.0000x reference)
//
#include <hip/hip_runtime.h>
#include <cstddef>

#define B_ 8
#define N_ 1024
#define C_ 512
#define H_ 8
#define DH_ 64
#define QKVLD 1536
#define SCALE_ 0.125f
#define NEG_ -1.0e9f

typedef _Float16 f16;
typedef f16  f16x4 __attribute__((ext_vector_type(4)));
typedef f16  f16x8 __attribute__((ext_vector_type(8)));
typedef float f32x4 __attribute__((ext_vector_type(4)));

static __device__ __forceinline__ f16x4 cvt4(float4 v) {
    f16x4 r; r[0] = (f16)v.x; r[1] = (f16)v.y; r[2] = (f16)v.z; r[3] = (f16)v.w;
    return r;
}

// ---------------------------------------------------------------------------
// f16-MFMA GEMM for QKV: C[M,Nn] = A[M,K] * Bt[Nn,K]^T + bias
// ---------------------------------------------------------------------------
__global__ __launch_bounds__(256) void k_qkv(const float* __restrict__ A,
                                             const float* __restrict__ Bt,
                                             const float* __restrict__ bias,
                                             float* __restrict__ Cc) {
    const int lda = C_, ldb = C_, ldc = QKVLD, K = C_;
    const int bm = blockIdx.y * 128, bn = blockIdx.x * 128;
    __shared__ __align__(16) f16 Af[128][40];
    __shared__ __align__(16) f16 Bf[128][40];
    const int tid  = threadIdx.x;
    const int wid  = tid >> 6, lane = tid & 63;
    const int wm   = (wid >> 1) * 64, wn = (wid & 1) * 64;
    const int lrow = lane & 15, kg = lane >> 4;
    const int ar = tid >> 3, ac = (tid & 7) << 2;

    f32x4 acc[4][4];
#pragma unroll
    for (int i = 0; i < 4; ++i)
#pragma unroll
        for (int j = 0; j < 4; ++j) acc[i][j] = (f32x4){0.f, 0.f, 0.f, 0.f};

    for (int k0 = 0; k0 < K; k0 += 32) {
        float4 a0 = *(const float4*)(A  + (size_t)(bm + ar     ) * lda + k0 + ac);
        float4 a1 = *(const float4*)(A  + (size_t)(bm + ar + 32) * lda + k0 + ac);
        float4 a2 = *(const float4*)(A  + (size_t)(bm + ar + 64) * lda + k0 + ac);
        float4 a3 = *(const float4*)(A  + (size_t)(bm + ar + 96) * lda + k0 + ac);
        float4 b0 = *(const float4*)(Bt + (size_t)(bn + ar     ) * ldb + k0 + ac);
        float4 b1 = *(const float4*)(Bt + (size_t)(bn + ar + 32) * ldb + k0 + ac);
        float4 b2 = *(const float4*)(Bt + (size_t)(bn + ar + 64) * ldb + k0 + ac);
        float4 b3 = *(const float4*)(Bt + (size_t)(bn + ar + 96) * ldb + k0 + ac);
        __syncthreads();
        *(f16x4*)&Af[ar     ][ac] = cvt4(a0);
        *(f16x4*)&Af[ar + 32][ac] = cvt4(a1);
        *(f16x4*)&Af[ar + 64][ac] = cvt4(a2);
        *(f16x4*)&Af[ar + 96][ac] = cvt4(a3);
        *(f16x4*)&Bf[ar     ][ac] = cvt4(b0);
        *(f16x4*)&Bf[ar + 32][ac] = cvt4(b1);
        *(f16x4*)&Bf[ar + 64][ac] = cvt4(b2);
        *(f16x4*)&Bf[ar + 96][ac] = cvt4(b3);
        __syncthreads();
        f16x8 af[4], bfv[4];
#pragma unroll
        for (int i = 0; i < 4; ++i)
            af[i] = *(const f16x8*)&Af[wm + i * 16 + lrow][kg * 8];
#pragma unroll
        for (int j = 0; j < 4; ++j)
            bfv[j] = *(const f16x8*)&Bf[wn + j * 16 + lrow][kg * 8];
#pragma unroll
        for (int i = 0; i < 4; ++i)
#pragma unroll
            for (int j = 0; j < 4; ++j)
                acc[i][j] = __builtin_amdgcn_mfma_f32_16x16x32_f16(af[i], bfv[j], acc[i][j], 0, 0, 0);
    }
#pragma unroll
    for (int j = 0; j < 4; ++j) {
        const int col = bn + wn + j * 16 + lrow;
        const float bv = bias[col];
#pragma unroll
        for (int i = 0; i < 4; ++i) {
            const int row0 = bm + wm + i * 16 + kg * 4;
#pragma unroll
            for (int r = 0; r < 4; ++r)
                Cc[(size_t)(row0 + r) * ldc + col] = acc[i][j][r] + bv;
        }
    }
}

// ---------------------------------------------------------------------------
// packs
// ---------------------------------------------------------------------------
__global__ __launch_bounds__(256) void pack_kf(const float* __restrict__ qkv,
                                               f16* __restrict__ kf) {
    const size_t i8 = ((size_t)blockIdx.x * 256 + threadIdx.x) << 3;
    const size_t row = i8 >> 9;
    const int c = (int)(i8 & 511);
    const float* src = qkv + row * QKVLD + C_ + c;
    float4 v0 = *(const float4*)src;
    float4 v1 = *(const float4*)(src + 4);
    f16x8 o;
    o[0]=(f16)v0.x; o[1]=(f16)v0.y; o[2]=(f16)v0.z; o[3]=(f16)v0.w;
    o[4]=(f16)v1.x; o[5]=(f16)v1.y; o[6]=(f16)v1.z; o[7]=(f16)v1.w;
    *(f16x8*)(kf + i8) = o;
}

__global__ __launch_bounds__(256) void pack_pw(const float* __restrict__ w,
                                               f16* __restrict__ wf) {
    const size_t i8 = ((size_t)blockIdx.x * 256 + threadIdx.x) << 3;
    const float* src = w + i8;
    float4 v0 = *(const float4*)src;
    float4 v1 = *(const float4*)(src + 4);
    f16x8 o;
    o[0]=(f16)v0.x; o[1]=(f16)v0.y; o[2]=(f16)v0.z; o[3]=(f16)v0.w;
    o[4]=(f16)v1.x; o[5]=(f16)v1.y; o[6]=(f16)v1.z; o[7]=(f16)v1.w;
    *(f16x8*)(wf + i8) = o;
}

__global__ __launch_bounds__(256) void pack_vt(const float* __restrict__ qkv,
                                               f16* __restrict__ vt) {
    const int z = blockIdx.x, b = z >> 3, h = z & 7;
    const float* V = qkv + (size_t)b * N_ * QKVLD + 2 * C_ + h * DH_;
    f16* O = vt + (size_t)z * DH_ * N_;
    __shared__ __align__(16) f16 T[64][72];
    const int t = threadIdx.x;
    for (int m0 = 0; m0 < N_; m0 += 64) {
#pragma unroll
        for (int it = 0; it < 4; ++it) {
            const int m = (t >> 4) + it * 16, d = (t & 15) * 4;
            float4 v = *(const float4*)(V + (size_t)(m0 + m) * QKVLD + d);
            T[d + 0][m] = (f16)v.x; T[d + 1][m] = (f16)v.y;
            T[d + 2][m] = (f16)v.z; T[d + 3][m] = (f16)v.w;
        }
        __syncthreads();
#pragma unroll
        for (int it = 0; it < 2; ++it) {
            const int d = (t >> 3) + it * 32, m = (t & 7) << 3;
            *(f16x8*)(O + (size_t)d * N_ + m0 + m) = *(const f16x8*)&T[d][m];
        }
        __syncthreads();
    }
}

// ---------------------------------------------------------------------------
// Kernel A: row stats (max, 1/sum) of premixed masked logits.
// Block = 512 thr (8 waves), q-tile 16, b = bid&7. K loads 1-deep pipelined.
// ---------------------------------------------------------------------------
__global__ __launch_bounds__(512, 4) void k_stats(
    const float* __restrict__ qkv,
    const f16*  __restrict__ kf,
    const float* __restrict__ mask,
    const float* __restrict__ pl_w, const float* __restrict__ pl_b,
    float* __restrict__ stats)
{
    __shared__ __align__(16) f16 Qs[16][520];
    __shared__ float Stat[8][8][2][16];

    const int flat = blockIdx.x;
    const int b = flat & 7, qt = flat >> 3;
    const int q0 = qt * 16;
    const int tid = threadIdx.x;
    const int w = tid >> 6, l = tid & 63;
    const int lc = l & 15, lr4 = l >> 4;

    {
        const int qrow = tid >> 5, c0 = (tid & 31) << 4;
        const float* src = qkv + (size_t)(b * N_ + q0 + qrow) * QKVLD + c0;
#pragma unroll
        for (int c = 0; c < 16; c += 4) {
            float4 v = *(const float4*)(src + c);
            f16x4 o;
            o[0]=(f16)(v.x*SCALE_); o[1]=(f16)(v.y*SCALE_);
            o[2]=(f16)(v.z*SCALE_); o[3]=(f16)(v.w*SCALE_);
            *(f16x4*)&Qs[qrow][c0 + c] = o;
        }
    }
    __syncthreads();

    const f16* kfb = kf + (size_t)b * N_ * C_;
    const float* maskb = mask + b * N_;

    float mx[8], sm[8];
#pragma unroll
    for (int g = 0; g < 8; ++g) { mx[g] = -3.0e38f; sm[g] = 0.f; }

    for (int mt = 0; mt < N_; mt += 128) {
        const int mb = mt + (w << 4);
        float4 mk4 = *(const float4*)(maskb + mb + (lr4 << 2));
        float mkv[4] = {(1.f-mk4.x)*NEG_, (1.f-mk4.y)*NEG_,
                        (1.f-mk4.z)*NEG_, (1.f-mk4.w)*NEG_};
        float a[8][4];
#pragma unroll
        for (int g = 0; g < 8; ++g) {
            const float bb = pl_b[g];
#pragma unroll
            for (int r = 0; r < 4; ++r) a[g][r] = bb + mkv[r];
        }
        const f16* krow = kfb + (size_t)(mb + lc) * C_ + (lr4 << 3);
        f16x8 kc0 = *(const f16x8*)(krow);
        f16x8 kc1 = *(const f16x8*)(krow + 32);
#pragma unroll
        for (int h = 0; h < 8; ++h) {
            f16x8 kn0, kn1;
            if (h < 7) {
                kn0 = *(const f16x8*)(krow + ((h + 1) << 6));
                kn1 = *(const f16x8*)(krow + ((h + 1) << 6) + 32);
            }
            f16x8 qa = *(const f16x8*)&Qs[lc][(h << 6) + (lr4 << 3)];
            f16x8 qb = *(const f16x8*)&Qs[lc][(h << 6) + 32 + (lr4 << 3)];
            f32x4 s = (f32x4){0.f, 0.f, 0.f, 0.f};
            s = __builtin_amdgcn_mfma_f32_16x16x32_f16(kc0, qa, s, 0, 0, 0);
            s = __builtin_amdgcn_mfma_f32_16x16x32_f16(kc1, qb, s, 0, 0, 0);
#pragma unroll
            for (int g = 0; g < 8; ++g) {
                const float wv = pl_w[(g << 3) + h];
#pragma unroll
                for (int r = 0; r < 4; ++r) a[g][r] = fmaf(wv, s[r], a[g][r]);
            }
            kc0 = kn0; kc1 = kn1;
        }
#pragma unroll
        for (int g = 0; g < 8; ++g) {
            float pm = fmaxf(fmaxf(a[g][0], a[g][1]), fmaxf(a[g][2], a[g][3]));
            float nm = fmaxf(mx[g], pm);
            float t  = sm[g] * __expf(mx[g] - nm);
#pragma unroll
            for (int r = 0; r < 4; ++r) t += __expf(a[g][r] - nm);
            sm[g] = t; mx[g] = nm;
        }
    }
#pragma unroll
    for (int g = 0; g < 8; ++g) {
#pragma unroll
        for (int off = 16; off < 64; off <<= 1) {
            float m2 = __shfl_xor(mx[g], off);
            float s2 = __shfl_xor(sm[g], off);
            float nm = fmaxf(mx[g], m2);
            sm[g] = sm[g] * __expf(mx[g] - nm) + s2 * __expf(m2 - nm);
            mx[g] = nm;
        }
    }
    if (l < 16) {
#pragma unroll
        for (int g = 0; g < 8; ++g) {
            Stat[w][g][0][l] = mx[g];
            Stat[w][g][1][l] = sm[g];
        }
    }
    __syncthreads();
    if (tid < 16) {
#pragma unroll
        for (int g = 0; g < 8; ++g) {
            float M = Stat[0][g][0][tid];
#pragma unroll
            for (int wv = 1; wv < 8; ++wv) M = fmaxf(M, Stat[wv][g][0][tid]);
            float S = 0.f;
#pragma unroll
            for (int wv = 0; wv < 8; ++wv)
                S += Stat[wv][g][1][tid] * __expf(Stat[wv][g][0][tid] - M);
            const size_t base = (size_t)(((b << 3) + g) << 1) * N_ + q0 + tid;
            stats[base] = M;
            stats[base + N_] = 1.f / S;
        }
    }
}

// ---------------------------------------------------------------------------
// Kernel B: recompute premixed logits, normalize, postmix -> Ps (f16),
// coalesced nontemporal attn2 dump, PV, fused proj.
// ---------------------------------------------------------------------------
__global__ __launch_bounds__(512, 4) void k_phase2(
    const float* __restrict__ qkv,
    const f16*  __restrict__ kf,
    const f16*  __restrict__ vt,
    const f16*  __restrict__ pwf,
    const float* __restrict__ mask,
    const float* __restrict__ pl_w, const float* __restrict__ pl_b,
    const float* __restrict__ pw_w, const float* __restrict__ pw_b,
    const float* __restrict__ proj_b,
    const float* __restrict__ stats,
    float* __restrict__ attn,
    float* __restrict__ out)
{
    __shared__ __align__(16) f16 Qs[16][520];
    __shared__ __align__(16) f16 Ps[8][16][136];

    const int flat = blockIdx.x;
    const int b = flat & 7, qt = flat >> 3;
    const int q0 = qt * 16;
    const int tid = threadIdx.x;
    const int w = tid >> 6, l = tid & 63;
    const int lc = l & 15, lr4 = l >> 4;

    {
        const int qrow = tid >> 5, c0 = (tid & 31) << 4;
        const float* src = qkv + (size_t)(b * N_ + q0 + qrow) * QKVLD + c0;
#pragma unroll
        for (int c = 0; c < 16; c += 4) {
            float4 v = *(const float4*)(src + c);
            f16x4 o;
            o[0]=(f16)(v.x*SCALE_); o[1]=(f16)(v.y*SCALE_);
            o[2]=(f16)(v.z*SCALE_); o[3]=(f16)(v.w*SCALE_);
            *(f16x4*)&Qs[qrow][c0 + c] = o;
        }
    }

    float mx[8], invs[8];
#pragma unroll
    for (int g = 0; g < 8; ++g) {
        const size_t base = (size_t)(((b << 3) + g) << 1) * N_ + q0 + lc;
        mx[g]   = stats[base];
        invs[g] = stats[base + N_];
    }
    __syncthreads();

    const f16* kfb = kf + (size_t)b * N_ * C_;
    const float* maskb = mask + b * N_;
    float* attnb = attn + (size_t)(b * H_) * N_ * N_;

    f32x4 O[4];
#pragma unroll
    for (int df = 0; df < 4; ++df) O[df] = (f32x4){0.f, 0.f, 0.f, 0.f};

    for (int mt = 0; mt < N_; mt += 128) {
        const int mb = mt + (w << 4);
        float4 mk4 = *(const float4*)(maskb + mb + (lr4 << 2));
        float mkv[4] = {(1.f-mk4.x)*NEG_, (1.f-mk4.y)*NEG_,
                        (1.f-mk4.z)*NEG_, (1.f-mk4.w)*NEG_};
        float a[8][4];
#pragma unroll
        for (int g = 0; g < 8; ++g) {
            const float bb = pl_b[g];
#pragma unroll
            for (int r = 0; r < 4; ++r) a[g][r] = bb + mkv[r];
        }
        const f16* krow = kfb + (size_t)(mb + lc) * C_ + (lr4 << 3);
        f16x8 kc0 = *(const f16x8*)(krow);
        f16x8 kc1 = *(const f16x8*)(krow + 32);
#pragma unroll
        for (int h = 0; h < 8; ++h) {
            f16x8 kn0, kn1;
            if (h < 7) {
                kn0 = *(const f16x8*)(krow + ((h + 1) << 6));
                kn1 = *(const f16x8*)(krow + ((h + 1) << 6) + 32);
            }
            f16x8 qa = *(const f16x8*)&Qs[lc][(h << 6) + (lr4 << 3)];
            f16x8 qb = *(const f16x8*)&Qs[lc][(h << 6) + 32 + (lr4 << 3)];
            f32x4 s = (f32x4){0.f, 0.f, 0.f, 0.f};
            s = __builtin_amdgcn_mfma_f32_16x16x32_f16(kc0, qa, s, 0, 0, 0);
            s = __builtin_amdgcn_mfma_f32_16x16x32_f16(kc1, qb, s, 0, 0, 0);
#pragma unroll
            for (int g = 0; g < 8; ++g) {
                const float wv = pl_w[(g << 3) + h];
#pragma unroll
                for (int r = 0; r < 4; ++r) a[g][r] = fmaf(wv, s[r], a[g][r]);
            }
            kc0 = kn0; kc1 = kn1;
        }
        float p[8][4];
#pragma unroll
        for (int g = 0; g < 8; ++g)
#pragma unroll
            for (int r = 0; r < 4; ++r)
                p[g][r] = __expf(a[g][r] - mx[g]) * invs[g];

#pragma unroll
        for (int gg = 0; gg < 8; ++gg) {
            const float bb = pw_b[gg];
            float o0 = bb, o1 = bb, o2 = bb, o3 = bb;
#pragma unroll
            for (int g = 0; g < 8; ++g) {
                const float wv = pw_w[(gg << 3) + g];
                o0 = fmaf(wv, p[g][0], o0);
                o1 = fmaf(wv, p[g][1], o1);
                o2 = fmaf(wv, p[g][2], o2);
                o3 = fmaf(wv, p[g][3], o3);
            }
            f16x4 ph; ph[0]=(f16)o0; ph[1]=(f16)o1; ph[2]=(f16)o2; ph[3]=(f16)o3;
            *(f16x4*)&Ps[gg][lc][(w << 4) + (lr4 << 2)] = ph;
        }
        __syncthreads();

        // coalesced nontemporal attn2 dump: wave w dumps head w's 16q x 128m
        {
            const int mseg = (l & 15) << 3;
            const int qb0 = l >> 4;
#pragma unroll
            for (int qq = 0; qq < 4; ++qq) {
                const int q = qb0 + (qq << 2);
                f16x8 v = *(const f16x8*)&Ps[w][q][mseg];
                f32x4 lo = (f32x4){(float)v[0], (float)v[1], (float)v[2], (float)v[3]};
                f32x4 hi = (f32x4){(float)v[4], (float)v[5], (float)v[6], (float)v[7]};
                float* dst = attnb + ((size_t)w * N_ + q0 + q) * N_ + mt + mseg;
                __builtin_nontemporal_store(lo, (f32x4*)dst);
                __builtin_nontemporal_store(hi, (f32x4*)(dst + 4));
            }
        }
        // PV: wave w, head w, 1-deep pipelined V loads
        {
            const f16* vg = vt + (size_t)(b * H_ + w) * DH_ * N_ + mt + (lr4 << 3);
            f16x8 va[4], vn[4];
#pragma unroll
            for (int df = 0; df < 4; ++df)
                va[df] = *(const f16x8*)(vg + (size_t)((df << 4) + lc) * N_);
#pragma unroll
            for (int kk = 0; kk < 4; ++kk) {
                if (kk < 3) {
#pragma unroll
                    for (int df = 0; df < 4; ++df)
                        vn[df] = *(const f16x8*)(vg + (size_t)((df << 4) + lc) * N_ + ((kk + 1) << 5));
                }
                f16x8 bf = *(const f16x8*)&Ps[w][lc][(kk << 5) + (lr4 << 3)];
#pragma unroll
                for (int df = 0; df < 4; ++df) {
                    O[df] = __builtin_amdgcn_mfma_f32_16x16x32_f16(va[df], bf, O[df], 0, 0, 0);
                    va[df] = vn[df];
                }
            }
        }
        __syncthreads();
    }

    // epilogue: o1 -> Qs (f16), fused proj
#pragma unroll
    for (int df = 0; df < 4; ++df) {
        f16x4 ph;
        ph[0]=(f16)O[df][0]; ph[1]=(f16)O[df][1];
        ph[2]=(f16)O[df][2]; ph[3]=(f16)O[df][3];
        *(f16x4*)&Qs[lc][(w << 6) + (df << 4) + (lr4 << 2)] = ph;
    }
    __syncthreads();

    {
        f32x4 acc[4];
#pragma unroll
        for (int cof = 0; cof < 4; ++cof) acc[cof] = (f32x4){0.f, 0.f, 0.f, 0.f};
        for (int ci = 0; ci < C_; ci += 32) {
            f16x8 bf = *(const f16x8*)&Qs[lc][ci + (lr4 << 3)];
#pragma unroll
            for (int cof = 0; cof < 4; ++cof) {
                f16x8 af = *(const f16x8*)(pwf + (size_t)((w << 6) + (cof << 4) + lc) * C_ + ci + (lr4 << 3));
                acc[cof] = __builtin_amdgcn_mfma_f32_16x16x32_f16(af, bf, acc[cof], 0, 0, 0);
            }
        }
        float* outb = out + (size_t)(b * N_ + q0) * C_;
#pragma unroll
        for (int cof = 0; cof < 4; ++cof) {
            const int co = (w << 6) + (cof << 4) + (lr4 << 2);
            float4 b4 = *(const float4*)(proj_b + co);
            float4 r;
            r.x = acc[cof][0] + b4.x;
            r.y = acc[cof][1] + b4.y;
            r.z = acc[cof][2] + b4.z;
            r.w = acc[cof][3] + b4.w;
            *(float4*)(outb + (size_t)lc * C_ + co) = r;
        }
    }
}

extern "C" void kernel_launch(void* const* d_in, const int* in_sizes, int n_in,
                              void* d_out, int out_size, void* d_ws, size_t ws_size,
                              hipStream_t stream)
{
    const float* x      = (const float*)d_in[0];
    const float* mask   = (const float*)d_in[1];
    const float* qkv_w  = (const float*)d_in[2];
    const float* qkv_b  = (const float*)d_in[3];
    const float* proj_w = (const float*)d_in[4];
    const float* proj_b = (const float*)d_in[5];
    const float* pl_w   = (const float*)d_in[6];
    const float* pl_b   = (const float*)d_in[7];
    const float* pw_w   = (const float*)d_in[8];
    const float* pw_b   = (const float*)d_in[9];

    float* out  = (float*)d_out;                        // [B,N,C]
    float* attn = out + (size_t)B_ * N_ * C_;           // [B,H,N,N]
    float* qkvb = (float*)d_ws;                         // 50.3 MB
    f16*   kf   = (f16*)(qkvb + (size_t)B_ * N_ * 3 * C_);  // 8.4 MB
    f16*   vt   = kf + (size_t)B_ * N_ * C_;                // 8.4 MB
    f16*   pwf  = vt + (size_t)B_ * N_ * C_;                // 0.5 MB
    float* stats = (float*)(pwf + (size_t)C_ * C_);         // [B][H][2][N] 0.5 MB
    (void)in_sizes; (void)n_in; (void)out_size; (void)ws_size;

    // 1) qkv = x @ qkv_w^T + qkv_b
    k_qkv<<<dim3(QKVLD / 128, B_ * N_ / 128), 256, 0, stream>>>(x, qkv_w, qkv_b, qkvb);

    // 2) packs
    pack_kf<<<dim3(2048), 256, 0, stream>>>(qkvb, kf);
    pack_vt<<<dim3(B_ * H_), 256, 0, stream>>>(qkvb, vt);
    pack_pw<<<dim3(128), 256, 0, stream>>>(proj_w, pwf);

    // 3) row stats (premix + mask + softmax max/sum)
    k_stats<<<dim3(512), 512, 0, stream>>>(qkvb, kf, mask, pl_w, pl_b, stats);

    // 4) normalize + postmix + attn write + PV + proj
    k_phase2<<<dim3(512), 512, 0, stream>>>(
        qkvb, kf, vt, pwf, mask, pl_w, pl_b, pw_w, pw_b, proj_b, stats, attn, out);
}

// Round 7
// 277.673 us; speedup vs baseline: 1.2291x; 1.2291x over previous
//
#include <hip/hip_runtime.h>
#include <cstddef>

#define B_ 8
#define N_ 1024
#define C_ 512
#define H_ 8
#define DH_ 64
#define QKVLD 1536
#define SCALE_ 0.125f
#define NEG_ -1.0e9f
#define ESHIFT 6.0f

typedef _Float16 f16;
typedef f16  f16x4 __attribute__((ext_vector_type(4)));
typedef f16  f16x8 __attribute__((ext_vector_type(8)));
typedef float f32x4 __attribute__((ext_vector_type(4)));

static __device__ __forceinline__ f16x4 cvt4(float4 v) {
    f16x4 r; r[0] = (f16)v.x; r[1] = (f16)v.y; r[2] = (f16)v.z; r[3] = (f16)v.w;
    return r;
}

// ---------------------------------------------------------------------------
// f16-MFMA GEMM for QKV: C[M,Nn] = A[M,K] * Bt[Nn,K]^T + bias
// ---------------------------------------------------------------------------
__global__ __launch_bounds__(256) void k_qkv(const float* __restrict__ A,
                                             const float* __restrict__ Bt,
                                             const float* __restrict__ bias,
                                             float* __restrict__ Cc) {
    const int lda = C_, ldb = C_, ldc = QKVLD, K = C_;
    const int bm = blockIdx.y * 128, bn = blockIdx.x * 128;
    __shared__ __align__(16) f16 Af[128][40];
    __shared__ __align__(16) f16 Bf[128][40];
    const int tid  = threadIdx.x;
    const int wid  = tid >> 6, lane = tid & 63;
    const int wm   = (wid >> 1) * 64, wn = (wid & 1) * 64;
    const int lrow = lane & 15, kg = lane >> 4;
    const int ar = tid >> 3, ac = (tid & 7) << 2;

    f32x4 acc[4][4];
#pragma unroll
    for (int i = 0; i < 4; ++i)
#pragma unroll
        for (int j = 0; j < 4; ++j) acc[i][j] = (f32x4){0.f, 0.f, 0.f, 0.f};

    for (int k0 = 0; k0 < K; k0 += 32) {
        float4 a0 = *(const float4*)(A  + (size_t)(bm + ar     ) * lda + k0 + ac);
        float4 a1 = *(const float4*)(A  + (size_t)(bm + ar + 32) * lda + k0 + ac);
        float4 a2 = *(const float4*)(A  + (size_t)(bm + ar + 64) * lda + k0 + ac);
        float4 a3 = *(const float4*)(A  + (size_t)(bm + ar + 96) * lda + k0 + ac);
        float4 b0 = *(const float4*)(Bt + (size_t)(bn + ar     ) * ldb + k0 + ac);
        float4 b1 = *(const float4*)(Bt + (size_t)(bn + ar + 32) * ldb + k0 + ac);
        float4 b2 = *(const float4*)(Bt + (size_t)(bn + ar + 64) * ldb + k0 + ac);
        float4 b3 = *(const float4*)(Bt + (size_t)(bn + ar + 96) * ldb + k0 + ac);
        __syncthreads();
        *(f16x4*)&Af[ar     ][ac] = cvt4(a0);
        *(f16x4*)&Af[ar + 32][ac] = cvt4(a1);
        *(f16x4*)&Af[ar + 64][ac] = cvt4(a2);
        *(f16x4*)&Af[ar + 96][ac] = cvt4(a3);
        *(f16x4*)&Bf[ar     ][ac] = cvt4(b0);
        *(f16x4*)&Bf[ar + 32][ac] = cvt4(b1);
        *(f16x4*)&Bf[ar + 64][ac] = cvt4(b2);
        *(f16x4*)&Bf[ar + 96][ac] = cvt4(b3);
        __syncthreads();
        f16x8 af[4], bfv[4];
#pragma unroll
        for (int i = 0; i < 4; ++i)
            af[i] = *(const f16x8*)&Af[wm + i * 16 + lrow][kg * 8];
#pragma unroll
        for (int j = 0; j < 4; ++j)
            bfv[j] = *(const f16x8*)&Bf[wn + j * 16 + lrow][kg * 8];
#pragma unroll
        for (int i = 0; i < 4; ++i)
#pragma unroll
            for (int j = 0; j < 4; ++j)
                acc[i][j] = __builtin_amdgcn_mfma_f32_16x16x32_f16(af[i], bfv[j], acc[i][j], 0, 0, 0);
    }
#pragma unroll
    for (int j = 0; j < 4; ++j) {
        const int col = bn + wn + j * 16 + lrow;
        const float bv = bias[col];
#pragma unroll
        for (int i = 0; i < 4; ++i) {
            const int row0 = bm + wm + i * 16 + kg * 4;
#pragma unroll
            for (int r = 0; r < 4; ++r)
                Cc[(size_t)(row0 + r) * ldc + col] = acc[i][j][r] + bv;
        }
    }
}

// ---------------------------------------------------------------------------
// packs
// ---------------------------------------------------------------------------
__global__ __launch_bounds__(256) void pack_kf(const float* __restrict__ qkv,
                                               f16* __restrict__ kf) {
    const size_t i8 = ((size_t)blockIdx.x * 256 + threadIdx.x) << 3;
    const size_t row = i8 >> 9;
    const int c = (int)(i8 & 511);
    const float* src = qkv + row * QKVLD + C_ + c;
    float4 v0 = *(const float4*)src;
    float4 v1 = *(const float4*)(src + 4);
    f16x8 o;
    o[0]=(f16)v0.x; o[1]=(f16)v0.y; o[2]=(f16)v0.z; o[3]=(f16)v0.w;
    o[4]=(f16)v1.x; o[5]=(f16)v1.y; o[6]=(f16)v1.z; o[7]=(f16)v1.w;
    *(f16x8*)(kf + i8) = o;
}

__global__ __launch_bounds__(256) void pack_pw(const float* __restrict__ w,
                                               f16* __restrict__ wf) {
    const size_t i8 = ((size_t)blockIdx.x * 256 + threadIdx.x) << 3;
    const float* src = w + i8;
    float4 v0 = *(const float4*)src;
    float4 v1 = *(const float4*)(src + 4);
    f16x8 o;
    o[0]=(f16)v0.x; o[1]=(f16)v0.y; o[2]=(f16)v0.z; o[3]=(f16)v0.w;
    o[4]=(f16)v1.x; o[5]=(f16)v1.y; o[6]=(f16)v1.z; o[7]=(f16)v1.w;
    *(f16x8*)(wf + i8) = o;
}

__global__ __launch_bounds__(256) void pack_vt(const float* __restrict__ qkv,
                                               f16* __restrict__ vt) {
    const int z = blockIdx.x, b = z >> 3, h = z & 7;
    const float* V = qkv + (size_t)b * N_ * QKVLD + 2 * C_ + h * DH_;
    f16* O = vt + (size_t)z * DH_ * N_;
    __shared__ __align__(16) f16 T[64][72];
    const int t = threadIdx.x;
    for (int m0 = 0; m0 < N_; m0 += 64) {
#pragma unroll
        for (int it = 0; it < 4; ++it) {
            const int m = (t >> 4) + it * 16, d = (t & 15) * 4;
            float4 v = *(const float4*)(V + (size_t)(m0 + m) * QKVLD + d);
            T[d + 0][m] = (f16)v.x; T[d + 1][m] = (f16)v.y;
            T[d + 2][m] = (f16)v.z; T[d + 3][m] = (f16)v.w;
        }
        __syncthreads();
#pragma unroll
        for (int it = 0; it < 2; ++it) {
            const int d = (t >> 3) + it * 32, m = (t & 7) << 3;
            *(f16x8*)(O + (size_t)d * N_ + m0 + m) = *(const f16x8*)&T[d][m];
        }
        __syncthreads();
    }
}

// ---------------------------------------------------------------------------
// Kernel A: QK^T + premix + exp(a-6) in one pass; store unnormalized expP
// (f16) to ws + row sums -> invS. K frags for all 8 heads fully prefetched.
// ---------------------------------------------------------------------------
__global__ __launch_bounds__(512, 3) void k_scorexp(
    const float* __restrict__ qkv,
    const f16*  __restrict__ kf,
    const float* __restrict__ mask,
    const float* __restrict__ pl_w, const float* __restrict__ pl_b,
    f16* __restrict__ p16,
    float* __restrict__ stats)
{
    __shared__ __align__(16) f16 Qs[16][520];
    __shared__ __align__(16) f16 Ps[8][16][136];
    __shared__ float Stat[8][8][16];

    const int flat = blockIdx.x;
    const int b = flat & 7, qt = flat >> 3;
    const int q0 = qt * 16;
    const int tid = threadIdx.x;
    const int w = tid >> 6, l = tid & 63;
    const int lc = l & 15, lr4 = l >> 4;

    {
        const int qrow = tid >> 5, c0 = (tid & 31) << 4;
        const float* src = qkv + (size_t)(b * N_ + q0 + qrow) * QKVLD + c0;
#pragma unroll
        for (int c = 0; c < 16; c += 4) {
            float4 v = *(const float4*)(src + c);
            f16x4 o;
            o[0]=(f16)(v.x*SCALE_); o[1]=(f16)(v.y*SCALE_);
            o[2]=(f16)(v.z*SCALE_); o[3]=(f16)(v.w*SCALE_);
            *(f16x4*)&Qs[qrow][c0 + c] = o;
        }
    }
    __syncthreads();

    const f16* kfb = kf + (size_t)b * N_ * C_;
    const float* maskb = mask + b * N_;

    float sm[8];
#pragma unroll
    for (int g = 0; g < 8; ++g) sm[g] = 0.f;

    for (int mt = 0; mt < N_; mt += 128) {
        const int mb = mt + (w << 4);
        float4 mk4 = *(const float4*)(maskb + mb + (lr4 << 2));
        float mkv[4] = {(1.f-mk4.x)*NEG_, (1.f-mk4.y)*NEG_,
                        (1.f-mk4.z)*NEG_, (1.f-mk4.w)*NEG_};
        float a[8][4];
#pragma unroll
        for (int g = 0; g < 8; ++g) {
            const float bb = pl_b[g];
#pragma unroll
            for (int r = 0; r < 4; ++r) a[g][r] = bb + mkv[r];
        }
        const f16* krow = kfb + (size_t)(mb + lc) * C_ + (lr4 << 3);
        f16x8 kfr[16];
#pragma unroll
        for (int t = 0; t < 16; ++t)
            kfr[t] = *(const f16x8*)(krow + (t << 5));
#pragma unroll
        for (int h = 0; h < 8; ++h) {
            f16x8 qa = *(const f16x8*)&Qs[lc][(h << 6) + (lr4 << 3)];
            f16x8 qb = *(const f16x8*)&Qs[lc][(h << 6) + 32 + (lr4 << 3)];
            f32x4 s = (f32x4){0.f, 0.f, 0.f, 0.f};
            s = __builtin_amdgcn_mfma_f32_16x16x32_f16(kfr[2*h    ], qa, s, 0, 0, 0);
            s = __builtin_amdgcn_mfma_f32_16x16x32_f16(kfr[2*h + 1], qb, s, 0, 0, 0);
#pragma unroll
            for (int g = 0; g < 8; ++g) {
                const float wv = pl_w[(g << 3) + h];
#pragma unroll
                for (int r = 0; r < 4; ++r) a[g][r] = fmaf(wv, s[r], a[g][r]);
            }
        }
#pragma unroll
        for (int g = 0; g < 8; ++g) {
            f16x4 ph;
#pragma unroll
            for (int r = 0; r < 4; ++r) {
                float e = __expf(a[g][r] - ESHIFT);
                sm[g] += e;
                ph[r] = (f16)e;
            }
            *(f16x4*)&Ps[g][lc][(w << 4) + (lr4 << 2)] = ph;
        }
        __syncthreads();
        // dump: wave w dumps head g=w, 16q x 128m, contiguous 256B runs
        {
            const int mseg = (l & 15) << 3;
            const int qb0 = l >> 4;
#pragma unroll
            for (int qq = 0; qq < 4; ++qq) {
                const int q = qb0 + (qq << 2);
                f16x8 v = *(const f16x8*)&Ps[w][q][mseg];
                f16* dst = p16 + (((size_t)(b * N_ + q0 + q) << 3) + w) * N_ + mt + mseg;
                __builtin_nontemporal_store(v, (f16x8*)dst);
            }
        }
        __syncthreads();
    }
    // sum reduce: in-wave over lr4 groups, then cross-wave via LDS
#pragma unroll
    for (int g = 0; g < 8; ++g) {
        sm[g] += __shfl_xor(sm[g], 16);
        sm[g] += __shfl_xor(sm[g], 32);
    }
    if (l < 16) {
#pragma unroll
        for (int g = 0; g < 8; ++g) Stat[w][g][l] = sm[g];
    }
    __syncthreads();
    if (tid < 16) {
#pragma unroll
        for (int g = 0; g < 8; ++g) {
            float S = 0.f;
#pragma unroll
            for (int wv = 0; wv < 8; ++wv) S += Stat[wv][g][tid];
            stats[((size_t)((b << 3) + g)) * N_ + q0 + tid] = 1.f / S;
        }
    }
}

// ---------------------------------------------------------------------------
// Kernel B: stream expP back, postmix (pw * invS folded), write attn2, PV,
// fused proj. Wave w owns head w end-to-end (no cross-wave PV dependency).
// ---------------------------------------------------------------------------
__global__ __launch_bounds__(512, 4) void k_post(
    const f16*  __restrict__ p16,
    const f16*  __restrict__ vt,
    const f16*  __restrict__ pwf,
    const float* __restrict__ pw_w, const float* __restrict__ pw_b,
    const float* __restrict__ proj_b,
    const float* __restrict__ stats,
    float* __restrict__ attn,
    float* __restrict__ out)
{
    __shared__ __align__(16) f16 Pl[8][16][68];
    __shared__ __align__(16) f16 Ps[8][16][68];
    __shared__ float iS[8][16];

    const int flat = blockIdx.x;
    const int b = flat & 7, qt = flat >> 3;
    const int q0 = qt * 16;
    const int tid = threadIdx.x;
    const int w = tid >> 6, l = tid & 63;
    const int lc = l & 15, lr4 = l >> 4;

    if (tid < 128) {
        const int g = tid >> 4, q = tid & 15;
        iS[g][q] = stats[((size_t)((b << 3) + g)) * N_ + q0 + q];
    }
    float Wg[8];
#pragma unroll
    for (int g = 0; g < 8; ++g) Wg[g] = pw_w[(w << 3) + g];
    const float bw = pw_b[w];

    f32x4 O[4];
#pragma unroll
    for (int df = 0; df < 4; ++df) O[df] = (f32x4){0.f, 0.f, 0.f, 0.f};

    float* attnb = attn + (size_t)(b * H_) * N_ * N_;
    const f16* vg = vt + (size_t)(b * H_ + w) * DH_ * N_;

    // cooperative Pl loader geometry: 128 rows (g,q) x 64 m, 32B/thread
    const int lrow = tid >> 2;
    const int lg = lrow >> 4, lq = lrow & 15;
    const int lseg = (tid & 3) << 4;
    const f16* lsrc = p16 + (((size_t)(b * N_ + q0 + lq) << 3) + lg) * N_ + lseg;

    for (int mt = 0; mt < N_; mt += 64) {
        __syncthreads();
        {
            f16x8 v0 = *(const f16x8*)(lsrc + mt);
            f16x8 v1 = *(const f16x8*)(lsrc + mt + 8);
            *(f16x8*)&Pl[lg][lq][lseg]     = v0;
            *(f16x8*)&Pl[lg][lq][lseg + 8] = v1;
        }
        __syncthreads();
        // postmix: wave w -> head w; lane: q = lr4 + 4*qq, m = lc*4
#pragma unroll
        for (int qq = 0; qq < 4; ++qq) {
            const int q = lr4 + (qq << 2);
            const int mc = lc << 2;
            float p0 = bw, p1 = bw, p2v = bw, p3 = bw;
#pragma unroll
            for (int g = 0; g < 8; ++g) {
                f16x4 pg = *(const f16x4*)&Pl[g][q][mc];
                const float wv = Wg[g] * iS[g][q];
                p0 = fmaf(wv, (float)pg[0], p0);
                p1 = fmaf(wv, (float)pg[1], p1);
                p2v = fmaf(wv, (float)pg[2], p2v);
                p3 = fmaf(wv, (float)pg[3], p3);
            }
            f32x4 r = (f32x4){p0, p1, p2v, p3};
            __builtin_nontemporal_store(r,
                (f32x4*)(attnb + ((size_t)w * N_ + q0 + q) * N_ + mt + mc));
            f16x4 ph; ph[0]=(f16)p0; ph[1]=(f16)p1; ph[2]=(f16)p2v; ph[3]=(f16)p3;
            *(f16x4*)&Ps[w][q][mc] = ph;
        }
        // PV: wave w consumes its own Ps[w] (same-wave LDS, program order)
#pragma unroll
        for (int kk = 0; kk < 2; ++kk) {
            f16x8 bf = *(const f16x8*)&Ps[w][lc][(kk << 5) + (lr4 << 3)];
#pragma unroll
            for (int df = 0; df < 4; ++df) {
                f16x8 af = *(const f16x8*)(vg + (size_t)((df << 4) + lc) * N_
                                           + mt + (kk << 5) + (lr4 << 3));
                O[df] = __builtin_amdgcn_mfma_f32_16x16x32_f16(af, bf, O[df], 0, 0, 0);
            }
        }
    }

    // epilogue: o1 tile -> (reused) Ps as [16][520] f16, fused proj
    __syncthreads();
    f16* o1s = (f16*)Ps;
#pragma unroll
    for (int df = 0; df < 4; ++df) {
        f16x4 ph;
        ph[0]=(f16)O[df][0]; ph[1]=(f16)O[df][1];
        ph[2]=(f16)O[df][2]; ph[3]=(f16)O[df][3];
        *(f16x4*)&o1s[lc * 520 + (w << 6) + (df << 4) + (lr4 << 2)] = ph;
    }
    __syncthreads();
    {
        f32x4 acc[4];
#pragma unroll
        for (int cof = 0; cof < 4; ++cof) acc[cof] = (f32x4){0.f, 0.f, 0.f, 0.f};
        for (int ci = 0; ci < C_; ci += 32) {
            f16x8 bf = *(const f16x8*)&o1s[lc * 520 + ci + (lr4 << 3)];
#pragma unroll
            for (int cof = 0; cof < 4; ++cof) {
                f16x8 af = *(const f16x8*)(pwf + (size_t)((w << 6) + (cof << 4) + lc) * C_ + ci + (lr4 << 3));
                acc[cof] = __builtin_amdgcn_mfma_f32_16x16x32_f16(af, bf, acc[cof], 0, 0, 0);
            }
        }
        float* outb = out + (size_t)(b * N_ + q0) * C_;
#pragma unroll
        for (int cof = 0; cof < 4; ++cof) {
            const int co = (w << 6) + (cof << 4) + (lr4 << 2);
            float4 b4 = *(const float4*)(proj_b + co);
            float4 r;
            r.x = acc[cof][0] + b4.x;
            r.y = acc[cof][1] + b4.y;
            r.z = acc[cof][2] + b4.z;
            r.w = acc[cof][3] + b4.w;
            *(float4*)(outb + (size_t)lc * C_ + co) = r;
        }
    }
}

extern "C" void kernel_launch(void* const* d_in, const int* in_sizes, int n_in,
                              void* d_out, int out_size, void* d_ws, size_t ws_size,
                              hipStream_t stream)
{
    const float* x      = (const float*)d_in[0];
    const float* mask   = (const float*)d_in[1];
    const float* qkv_w  = (const float*)d_in[2];
    const float* qkv_b  = (const float*)d_in[3];
    const float* proj_w = (const float*)d_in[4];
    const float* proj_b = (const float*)d_in[5];
    const float* pl_w   = (const float*)d_in[6];
    const float* pl_b   = (const float*)d_in[7];
    const float* pw_w   = (const float*)d_in[8];
    const float* pw_b   = (const float*)d_in[9];

    float* out  = (float*)d_out;                        // [B,N,C]
    float* attn = out + (size_t)B_ * N_ * C_;           // [B,H,N,N]
    float* qkvb = (float*)d_ws;                         // 50.3 MB
    f16*   kf   = (f16*)(qkvb + (size_t)B_ * N_ * 3 * C_);  // 8.4 MB
    f16*   vt   = kf + (size_t)B_ * N_ * C_;                // 8.4 MB
    f16*   pwf  = vt + (size_t)B_ * N_ * C_;                // 0.5 MB
    float* stats = (float*)(pwf + (size_t)C_ * C_);         // [B*H][N] invS, 0.25 MB
    f16*   p16  = (f16*)(stats + (size_t)B_ * H_ * N_);     // [B,N,H,N] f16, 134 MB
    (void)in_sizes; (void)n_in; (void)out_size; (void)ws_size;

    // 1) qkv = x @ qkv_w^T + qkv_b
    k_qkv<<<dim3(QKVLD / 128, B_ * N_ / 128), 256, 0, stream>>>(x, qkv_w, qkv_b, qkvb);

    // 2) packs
    pack_kf<<<dim3(2048), 256, 0, stream>>>(qkvb, kf);
    pack_vt<<<dim3(B_ * H_), 256, 0, stream>>>(qkvb, vt);
    pack_pw<<<dim3(128), 256, 0, stream>>>(proj_w, pwf);

    // 3) QK^T + premix + exp -> p16 (unnormalized), invS
    k_scorexp<<<dim3(512), 512, 0, stream>>>(qkvb, kf, mask, pl_w, pl_b, p16, stats);

    // 4) postmix + attn write + PV + proj
    k_post<<<dim3(512), 512, 0, stream>>>(
        p16, vt, pwf, pw_w, pw_b, proj_b, stats, attn, out);
}

// Round 8
// 273.581 us; speedup vs baseline: 1.2475x; 1.0150x over previous
//
#include <hip/hip_runtime.h>
#include <cstddef>

#define B_ 8
#define N_ 1024
#define C_ 512
#define H_ 8
#define DH_ 64
#define QKVLD 1536
#define SCALE_ 0.125f
#define NEG_ -1.0e9f
#define ESHIFT 6.0f

typedef _Float16 f16;
typedef f16  f16x4 __attribute__((ext_vector_type(4)));
typedef f16  f16x8 __attribute__((ext_vector_type(8)));
typedef float f32x4 __attribute__((ext_vector_type(4)));

static __device__ __forceinline__ f16x4 cvt4(float4 v) {
    f16x4 r; r[0] = (f16)v.x; r[1] = (f16)v.y; r[2] = (f16)v.z; r[3] = (f16)v.w;
    return r;
}

// ---------------------------------------------------------------------------
// f16-MFMA GEMM for QKV: C[M,Nn] = A[M,K] * Bt[Nn,K]^T + bias
// ---------------------------------------------------------------------------
__global__ __launch_bounds__(256) void k_qkv(const float* __restrict__ A,
                                             const float* __restrict__ Bt,
                                             const float* __restrict__ bias,
                                             float* __restrict__ Cc) {
    const int lda = C_, ldb = C_, ldc = QKVLD, K = C_;
    const int bm = blockIdx.y * 128, bn = blockIdx.x * 128;
    __shared__ __align__(16) f16 Af[128][40];
    __shared__ __align__(16) f16 Bf[128][40];
    const int tid  = threadIdx.x;
    const int wid  = tid >> 6, lane = tid & 63;
    const int wm   = (wid >> 1) * 64, wn = (wid & 1) * 64;
    const int lrow = lane & 15, kg = lane >> 4;
    const int ar = tid >> 3, ac = (tid & 7) << 2;

    f32x4 acc[4][4];
#pragma unroll
    for (int i = 0; i < 4; ++i)
#pragma unroll
        for (int j = 0; j < 4; ++j) acc[i][j] = (f32x4){0.f, 0.f, 0.f, 0.f};

    for (int k0 = 0; k0 < K; k0 += 32) {
        float4 a0 = *(const float4*)(A  + (size_t)(bm + ar     ) * lda + k0 + ac);
        float4 a1 = *(const float4*)(A  + (size_t)(bm + ar + 32) * lda + k0 + ac);
        float4 a2 = *(const float4*)(A  + (size_t)(bm + ar + 64) * lda + k0 + ac);
        float4 a3 = *(const float4*)(A  + (size_t)(bm + ar + 96) * lda + k0 + ac);
        float4 b0 = *(const float4*)(Bt + (size_t)(bn + ar     ) * ldb + k0 + ac);
        float4 b1 = *(const float4*)(Bt + (size_t)(bn + ar + 32) * ldb + k0 + ac);
        float4 b2 = *(const float4*)(Bt + (size_t)(bn + ar + 64) * ldb + k0 + ac);
        float4 b3 = *(const float4*)(Bt + (size_t)(bn + ar + 96) * ldb + k0 + ac);
        __syncthreads();
        *(f16x4*)&Af[ar     ][ac] = cvt4(a0);
        *(f16x4*)&Af[ar + 32][ac] = cvt4(a1);
        *(f16x4*)&Af[ar + 64][ac] = cvt4(a2);
        *(f16x4*)&Af[ar + 96][ac] = cvt4(a3);
        *(f16x4*)&Bf[ar     ][ac] = cvt4(b0);
        *(f16x4*)&Bf[ar + 32][ac] = cvt4(b1);
        *(f16x4*)&Bf[ar + 64][ac] = cvt4(b2);
        *(f16x4*)&Bf[ar + 96][ac] = cvt4(b3);
        __syncthreads();
        f16x8 af[4], bfv[4];
#pragma unroll
        for (int i = 0; i < 4; ++i)
            af[i] = *(const f16x8*)&Af[wm + i * 16 + lrow][kg * 8];
#pragma unroll
        for (int j = 0; j < 4; ++j)
            bfv[j] = *(const f16x8*)&Bf[wn + j * 16 + lrow][kg * 8];
#pragma unroll
        for (int i = 0; i < 4; ++i)
#pragma unroll
            for (int j = 0; j < 4; ++j)
                acc[i][j] = __builtin_amdgcn_mfma_f32_16x16x32_f16(af[i], bfv[j], acc[i][j], 0, 0, 0);
    }
#pragma unroll
    for (int j = 0; j < 4; ++j) {
        const int col = bn + wn + j * 16 + lrow;
        const float bv = bias[col];
#pragma unroll
        for (int i = 0; i < 4; ++i) {
            const int row0 = bm + wm + i * 16 + kg * 4;
#pragma unroll
            for (int r = 0; r < 4; ++r)
                Cc[(size_t)(row0 + r) * ldc + col] = acc[i][j][r] + bv;
        }
    }
}

// ---------------------------------------------------------------------------
// packs
// ---------------------------------------------------------------------------
__global__ __launch_bounds__(256) void pack_kf(const float* __restrict__ qkv,
                                               f16* __restrict__ kf) {
    const size_t i8 = ((size_t)blockIdx.x * 256 + threadIdx.x) << 3;
    const size_t row = i8 >> 9;
    const int c = (int)(i8 & 511);
    const float* src = qkv + row * QKVLD + C_ + c;
    float4 v0 = *(const float4*)src;
    float4 v1 = *(const float4*)(src + 4);
    f16x8 o;
    o[0]=(f16)v0.x; o[1]=(f16)v0.y; o[2]=(f16)v0.z; o[3]=(f16)v0.w;
    o[4]=(f16)v1.x; o[5]=(f16)v1.y; o[6]=(f16)v1.z; o[7]=(f16)v1.w;
    *(f16x8*)(kf + i8) = o;
}

__global__ __launch_bounds__(256) void pack_pw(const float* __restrict__ w,
                                               f16* __restrict__ wf) {
    const size_t i8 = ((size_t)blockIdx.x * 256 + threadIdx.x) << 3;
    const float* src = w + i8;
    float4 v0 = *(const float4*)src;
    float4 v1 = *(const float4*)(src + 4);
    f16x8 o;
    o[0]=(f16)v0.x; o[1]=(f16)v0.y; o[2]=(f16)v0.z; o[3]=(f16)v0.w;
    o[4]=(f16)v1.x; o[5]=(f16)v1.y; o[6]=(f16)v1.z; o[7]=(f16)v1.w;
    *(f16x8*)(wf + i8) = o;
}

__global__ __launch_bounds__(256) void pack_vt(const float* __restrict__ qkv,
                                               f16* __restrict__ vt) {
    const int z = blockIdx.x, b = z >> 3, h = z & 7;
    const float* V = qkv + (size_t)b * N_ * QKVLD + 2 * C_ + h * DH_;
    f16* O = vt + (size_t)z * DH_ * N_;
    __shared__ __align__(16) f16 T[64][72];
    const int t = threadIdx.x;
    for (int m0 = 0; m0 < N_; m0 += 64) {
#pragma unroll
        for (int it = 0; it < 4; ++it) {
            const int m = (t >> 4) + it * 16, d = (t & 15) * 4;
            float4 v = *(const float4*)(V + (size_t)(m0 + m) * QKVLD + d);
            T[d + 0][m] = (f16)v.x; T[d + 1][m] = (f16)v.y;
            T[d + 2][m] = (f16)v.z; T[d + 3][m] = (f16)v.w;
        }
        __syncthreads();
#pragma unroll
        for (int it = 0; it < 2; ++it) {
            const int d = (t >> 3) + it * 32, m = (t & 7) << 3;
            *(f16x8*)(O + (size_t)d * N_ + m0 + m) = *(const f16x8*)&T[d][m];
        }
        __syncthreads();
    }
}

// ---------------------------------------------------------------------------
// Kernel A: QK^T + premix + exp(a-6) in one pass; store unnormalized expP
// (f16) to ws + row sums -> invS. K frags for all 8 heads fully prefetched.
// ---------------------------------------------------------------------------
__global__ __launch_bounds__(512, 3) void k_scorexp(
    const float* __restrict__ qkv,
    const f16*  __restrict__ kf,
    const float* __restrict__ mask,
    const float* __restrict__ pl_w, const float* __restrict__ pl_b,
    f16* __restrict__ p16,
    float* __restrict__ stats)
{
    __shared__ __align__(16) f16 Qs[16][520];
    __shared__ __align__(16) f16 Ps[8][16][136];
    __shared__ float Stat[8][8][16];

    const int flat = blockIdx.x;
    const int b = flat & 7, qt = flat >> 3;
    const int q0 = qt * 16;
    const int tid = threadIdx.x;
    const int w = tid >> 6, l = tid & 63;
    const int lc = l & 15, lr4 = l >> 4;

    {
        const int qrow = tid >> 5, c0 = (tid & 31) << 4;
        const float* src = qkv + (size_t)(b * N_ + q0 + qrow) * QKVLD + c0;
#pragma unroll
        for (int c = 0; c < 16; c += 4) {
            float4 v = *(const float4*)(src + c);
            f16x4 o;
            o[0]=(f16)(v.x*SCALE_); o[1]=(f16)(v.y*SCALE_);
            o[2]=(f16)(v.z*SCALE_); o[3]=(f16)(v.w*SCALE_);
            *(f16x4*)&Qs[qrow][c0 + c] = o;
        }
    }
    __syncthreads();

    const f16* kfb = kf + (size_t)b * N_ * C_;
    const float* maskb = mask + b * N_;

    float sm[8];
#pragma unroll
    for (int g = 0; g < 8; ++g) sm[g] = 0.f;

    for (int mt = 0; mt < N_; mt += 128) {
        const int mb = mt + (w << 4);
        float4 mk4 = *(const float4*)(maskb + mb + (lr4 << 2));
        float mkv[4] = {(1.f-mk4.x)*NEG_, (1.f-mk4.y)*NEG_,
                        (1.f-mk4.z)*NEG_, (1.f-mk4.w)*NEG_};
        float a[8][4];
#pragma unroll
        for (int g = 0; g < 8; ++g) {
            const float bb = pl_b[g];
#pragma unroll
            for (int r = 0; r < 4; ++r) a[g][r] = bb + mkv[r];
        }
        const f16* krow = kfb + (size_t)(mb + lc) * C_ + (lr4 << 3);
        f16x8 kfr[16];
#pragma unroll
        for (int t = 0; t < 16; ++t)
            kfr[t] = *(const f16x8*)(krow + (t << 5));
#pragma unroll
        for (int h = 0; h < 8; ++h) {
            f16x8 qa = *(const f16x8*)&Qs[lc][(h << 6) + (lr4 << 3)];
            f16x8 qb = *(const f16x8*)&Qs[lc][(h << 6) + 32 + (lr4 << 3)];
            f32x4 s = (f32x4){0.f, 0.f, 0.f, 0.f};
            s = __builtin_amdgcn_mfma_f32_16x16x32_f16(kfr[2*h    ], qa, s, 0, 0, 0);
            s = __builtin_amdgcn_mfma_f32_16x16x32_f16(kfr[2*h + 1], qb, s, 0, 0, 0);
#pragma unroll
            for (int g = 0; g < 8; ++g) {
                const float wv = pl_w[(g << 3) + h];
#pragma unroll
                for (int r = 0; r < 4; ++r) a[g][r] = fmaf(wv, s[r], a[g][r]);
            }
        }
#pragma unroll
        for (int g = 0; g < 8; ++g) {
            f16x4 ph;
#pragma unroll
            for (int r = 0; r < 4; ++r) {
                float e = __expf(a[g][r] - ESHIFT);
                sm[g] += e;
                ph[r] = (f16)e;
            }
            *(f16x4*)&Ps[g][lc][(w << 4) + (lr4 << 2)] = ph;
        }
        __syncthreads();
        // dump: wave w dumps head g=w, 16q x 128m, contiguous 256B runs
        {
            const int mseg = (l & 15) << 3;
            const int qb0 = l >> 4;
#pragma unroll
            for (int qq = 0; qq < 4; ++qq) {
                const int q = qb0 + (qq << 2);
                f16x8 v = *(const f16x8*)&Ps[w][q][mseg];
                f16* dst = p16 + (((size_t)(b * N_ + q0 + q) << 3) + w) * N_ + mt + mseg;
                __builtin_nontemporal_store(v, (f16x8*)dst);
            }
        }
        __syncthreads();
    }
    // sum reduce: in-wave over lr4 groups, then cross-wave via LDS
#pragma unroll
    for (int g = 0; g < 8; ++g) {
        sm[g] += __shfl_xor(sm[g], 16);
        sm[g] += __shfl_xor(sm[g], 32);
    }
    if (l < 16) {
#pragma unroll
        for (int g = 0; g < 8; ++g) Stat[w][g][l] = sm[g];
    }
    __syncthreads();
    if (tid < 16) {
#pragma unroll
        for (int g = 0; g < 8; ++g) {
            float S = 0.f;
#pragma unroll
            for (int wv = 0; wv < 8; ++wv) S += Stat[wv][g][tid];
            stats[((size_t)((b << 3) + g)) * N_ + q0 + tid] = 1.f / S;
        }
    }
}

// ---------------------------------------------------------------------------
// Kernel B: stream expP back (L3), postmix (pw*invS folded), write attn2, PV,
// fused proj. Pl is a 2-deep LDS double buffer with register prefetch: loads
// for slab t+1 issue BEFORE slab t's compute, ds_write after -> one barrier
// per slab, L3 latency hidden under compute (T14 async-STAGE).
// ---------------------------------------------------------------------------
__global__ __launch_bounds__(512, 4) void k_post(
    const f16*  __restrict__ p16,
    const f16*  __restrict__ vt,
    const f16*  __restrict__ pwf,
    const float* __restrict__ pw_w, const float* __restrict__ pw_b,
    const float* __restrict__ proj_b,
    const float* __restrict__ stats,
    float* __restrict__ attn,
    float* __restrict__ out)
{
    __shared__ __align__(16) f16 Pl[2][8][16][68];
    __shared__ __align__(16) f16 Ps[8][16][68];
    __shared__ float iS[8][16];

    const int flat = blockIdx.x;
    const int b = flat & 7, qt = flat >> 3;
    const int q0 = qt * 16;
    const int tid = threadIdx.x;
    const int w = tid >> 6, l = tid & 63;
    const int lc = l & 15, lr4 = l >> 4;

    if (tid < 128) {
        const int g = tid >> 4, q = tid & 15;
        iS[g][q] = stats[((size_t)((b << 3) + g)) * N_ + q0 + q];
    }
    float Wg[8];
#pragma unroll
    for (int g = 0; g < 8; ++g) Wg[g] = pw_w[(w << 3) + g];
    const float bw = pw_b[w];

    f32x4 O[4];
#pragma unroll
    for (int df = 0; df < 4; ++df) O[df] = (f32x4){0.f, 0.f, 0.f, 0.f};

    float* attnb = attn + (size_t)(b * H_) * N_ * N_;
    const f16* vg = vt + (size_t)(b * H_ + w) * DH_ * N_;

    // cooperative Pl loader geometry: 128 rows (g,q) x 64 m, 32B/thread
    const int lrow = tid >> 2;
    const int lg = lrow >> 4, lq = lrow & 15;
    const int lseg = (tid & 3) << 4;
    const f16* lsrc = p16 + (((size_t)(b * N_ + q0 + lq) << 3) + lg) * N_ + lseg;

    // prologue: stage slab 0
    {
        f16x8 c0 = *(const f16x8*)(lsrc);
        f16x8 c1 = *(const f16x8*)(lsrc + 8);
        *(f16x8*)&Pl[0][lg][lq][lseg]     = c0;
        *(f16x8*)&Pl[0][lg][lq][lseg + 8] = c1;
    }
    __syncthreads();

    int cur = 0;
    for (int mt = 0; mt < N_; mt += 64) {
        // issue next slab's loads (consumed after compute)
        f16x8 n0, n1;
        const bool more = (mt + 64) < N_;
        if (more) {
            n0 = *(const f16x8*)(lsrc + mt + 64);
            n1 = *(const f16x8*)(lsrc + mt + 64 + 8);
        }
        // postmix: wave w -> head w; lane: q = lr4 + 4*qq, m = lc*4
#pragma unroll
        for (int qq = 0; qq < 4; ++qq) {
            const int q = lr4 + (qq << 2);
            const int mc = lc << 2;
            float p0 = bw, p1 = bw, p2v = bw, p3 = bw;
#pragma unroll
            for (int g = 0; g < 8; ++g) {
                f16x4 pg = *(const f16x4*)&Pl[cur][g][q][mc];
                const float wv = Wg[g] * iS[g][q];
                p0 = fmaf(wv, (float)pg[0], p0);
                p1 = fmaf(wv, (float)pg[1], p1);
                p2v = fmaf(wv, (float)pg[2], p2v);
                p3 = fmaf(wv, (float)pg[3], p3);
            }
            f32x4 r = (f32x4){p0, p1, p2v, p3};
            __builtin_nontemporal_store(r,
                (f32x4*)(attnb + ((size_t)w * N_ + q0 + q) * N_ + mt + mc));
            f16x4 ph; ph[0]=(f16)p0; ph[1]=(f16)p1; ph[2]=(f16)p2v; ph[3]=(f16)p3;
            *(f16x4*)&Ps[w][q][mc] = ph;
        }
        // PV: wave w consumes its own Ps[w] (same-wave LDS, program order)
#pragma unroll
        for (int kk = 0; kk < 2; ++kk) {
            f16x8 bf = *(const f16x8*)&Ps[w][lc][(kk << 5) + (lr4 << 3)];
#pragma unroll
            for (int df = 0; df < 4; ++df) {
                f16x8 af = *(const f16x8*)(vg + (size_t)((df << 4) + lc) * N_
                                           + mt + (kk << 5) + (lr4 << 3));
                O[df] = __builtin_amdgcn_mfma_f32_16x16x32_f16(af, bf, O[df], 0, 0, 0);
            }
        }
        // stage next slab into the other buffer; one barrier per slab
        if (more) {
            *(f16x8*)&Pl[cur ^ 1][lg][lq][lseg]     = n0;
            *(f16x8*)&Pl[cur ^ 1][lg][lq][lseg + 8] = n1;
        }
        __syncthreads();
        cur ^= 1;
    }

    // epilogue: o1 tile -> (reused) Ps as [16][520] f16, fused proj
    f16* o1s = (f16*)Ps;
#pragma unroll
    for (int df = 0; df < 4; ++df) {
        f16x4 ph;
        ph[0]=(f16)O[df][0]; ph[1]=(f16)O[df][1];
        ph[2]=(f16)O[df][2]; ph[3]=(f16)O[df][3];
        *(f16x4*)&o1s[lc * 520 + (w << 6) + (df << 4) + (lr4 << 2)] = ph;
    }
    __syncthreads();
    {
        f32x4 acc[4];
#pragma unroll
        for (int cof = 0; cof < 4; ++cof) acc[cof] = (f32x4){0.f, 0.f, 0.f, 0.f};
        for (int ci = 0; ci < C_; ci += 32) {
            f16x8 bf = *(const f16x8*)&o1s[lc * 520 + ci + (lr4 << 3)];
#pragma unroll
            for (int cof = 0; cof < 4; ++cof) {
                f16x8 af = *(const f16x8*)(pwf + (size_t)((w << 6) + (cof << 4) + lc) * C_ + ci + (lr4 << 3));
                acc[cof] = __builtin_amdgcn_mfma_f32_16x16x32_f16(af, bf, acc[cof], 0, 0, 0);
            }
        }
        float* outb = out + (size_t)(b * N_ + q0) * C_;
#pragma unroll
        for (int cof = 0; cof < 4; ++cof) {
            const int co = (w << 6) + (cof << 4) + (lr4 << 2);
            float4 b4 = *(const float4*)(proj_b + co);
            float4 r;
            r.x = acc[cof][0] + b4.x;
            r.y = acc[cof][1] + b4.y;
            r.z = acc[cof][2] + b4.z;
            r.w = acc[cof][3] + b4.w;
            *(float4*)(outb + (size_t)lc * C_ + co) = r;
        }
    }
}

extern "C" void kernel_launch(void* const* d_in, const int* in_sizes, int n_in,
                              void* d_out, int out_size, void* d_ws, size_t ws_size,
                              hipStream_t stream)
{
    const float* x      = (const float*)d_in[0];
    const float* mask   = (const float*)d_in[1];
    const float* qkv_w  = (const float*)d_in[2];
    const float* qkv_b  = (const float*)d_in[3];
    const float* proj_w = (const float*)d_in[4];
    const float* proj_b = (const float*)d_in[5];
    const float* pl_w   = (const float*)d_in[6];
    const float* pl_b   = (const float*)d_in[7];
    const float* pw_w   = (const float*)d_in[8];
    const float* pw_b   = (const float*)d_in[9];

    float* out  = (float*)d_out;                        // [B,N,C]
    float* attn = out + (size_t)B_ * N_ * C_;           // [B,H,N,N]
    float* qkvb = (float*)d_ws;                         // 50.3 MB
    f16*   kf   = (f16*)(qkvb + (size_t)B_ * N_ * 3 * C_);  // 8.4 MB
    f16*   vt   = kf + (size_t)B_ * N_ * C_;                // 8.4 MB
    f16*   pwf  = vt + (size_t)B_ * N_ * C_;                // 0.5 MB
    float* stats = (float*)(pwf + (size_t)C_ * C_);         // [B*H][N] invS, 0.25 MB
    f16*   p16  = (f16*)(stats + (size_t)B_ * H_ * N_);     // [B,N,H,N] f16, 134 MB
    (void)in_sizes; (void)n_in; (void)out_size; (void)ws_size;

    // 1) qkv = x @ qkv_w^T + qkv_b
    k_qkv<<<dim3(QKVLD / 128, B_ * N_ / 128), 256, 0, stream>>>(x, qkv_w, qkv_b, qkvb);

    // 2) packs
    pack_kf<<<dim3(2048), 256, 0, stream>>>(qkvb, kf);
    pack_vt<<<dim3(B_ * H_), 256, 0, stream>>>(qkvb, vt);
    pack_pw<<<dim3(128), 256, 0, stream>>>(proj_w, pwf);

    // 3) QK^T + premix + exp -> p16 (unnormalized), invS
    k_scorexp<<<dim3(512), 512, 0, stream>>>(qkvb, kf, mask, pl_w, pl_b, p16, stats);

    // 4) postmix + attn write + PV + proj
    k_post<<<dim3(512), 512, 0, stream>>>(
        p16, vt, pwf, pw_w, pw_b, proj_b, stats, attn, out);
}